// Round 7
// baseline (161.005 us; speedup 1.0000x reference)
//
#include <hip/hip_runtime.h>
#include <hip/hip_bf16.h>

// out[i] = 10 * min_j ||x_i - y_j||, x: 8192x96 f32, y: 65536x96 f32.
// sq = x2[i] + (y2[j] - 2*x.y): bf16 MFMA computes (y2 - 2*x.y) by pre-scaling
// train by -2 (exact in bf16) and preloading y2 as the MFMA C operand.
// R7: R6 was LDS-BW-bound (281 B/cyc demand vs 128 peak -> 52% MfmaUtil).
// Move A traffic to the TCP pipe: prep stores train in FRAGMENT-MAJOR order
// (16-row group x kb x lane x 8), so each wave a-frag is one contiguous 1KB
// coalesced global load (52.8 B/cyc < 64 B/cyc L1 peak). bq stays register-
// resident via volatile (R4/R5: compiler otherwise sinks it into the loop).
// y2 chunk staged once to LDS (4KB); no per-tile barriers.

typedef __attribute__((ext_vector_type(8))) short bf16x8;
typedef __attribute__((ext_vector_type(4))) float f32x4;

#define NQ 8192
#define NT 65536
#define KD 96
#define QB 256            // queries per WG: 4 waves x 64
#define TSPLIT 64         // train chunks; chunk t -> XCD t%8 (1.6 MB/XCD L2)
#define TCHUNK (NT / TSPLIT)   // 1024 rows per WG
#define NTT (TCHUNK / 16)      // 64 row-tiles per WG
#define GRP_USH 1536      // ushorts per 16-row fragment group (3 kb x 64 x 8)

static __device__ __forceinline__ ushort f2bf(float f) {
  unsigned u = __float_as_uint(f);
  return (ushort)((u + 0x7fffu + ((u >> 16) & 1u)) >> 16);
}
static __device__ __forceinline__ unsigned pk2(float a, float b) {
  return (unsigned)f2bf(a) | ((unsigned)f2bf(b) << 16);
}

// Thread t owns float4s [6t, 6t+6) of its block's 64 rows = one quarter-row.
// Row norm = quad shuffle-reduce. Queries stored row-major; train stored
// FRAGMENT-MAJOR: ushort off = (grp*3 + kb)*512 + (quad*16 + (row&15))*8 + j.
__global__ __launch_bounds__(256) void prep_kernel(
    const float* __restrict__ qf, const float* __restrict__ tf,
    ushort* __restrict__ qbf, ushort* __restrict__ tbf,
    float* __restrict__ x2, float* __restrict__ y2,
    float* __restrict__ outp)
{
  const int tid = threadIdx.x;
  const int b = blockIdx.x;
  const bool isq = b < (NQ / 64);
  const int rb = isq ? b : b - (NQ / 64);
  const int row = rb * 64 + (tid >> 2);
  const float4* src = (const float4*)((isq ? qf : tf) + (size_t)row * KD) + (tid & 3) * 6;
  const float scale = isq ? 1.0f : -2.0f;

  float s = 0.0f;
  #pragma unroll
  for (int i = 0; i < 6; ++i) {
    float4 v = src[i];
    s += v.x * v.x + v.y * v.y + v.z * v.z + v.w * v.w;
    uint2 p; p.x = pk2(v.x * scale, v.y * scale); p.y = pk2(v.z * scale, v.w * scale);
    int q4 = (tid & 3) * 6 + i;            // float4 index in row, 0..23
    if (isq) {
      *(uint2*)(qbf + (size_t)row * KD + q4 * 4) = p;
    } else {
      int kb = q4 >> 3, quad = (q4 >> 1) & 3, jh = q4 & 1;
      size_t off = ((size_t)(row >> 4) * 3 + kb) * 512 +
                   (quad * 16 + (row & 15)) * 8 + jh * 4;
      *(uint2*)(tbf + off) = p;
    }
  }
  s += __shfl_xor(s, 1, 64);
  s += __shfl_xor(s, 2, 64);
  if ((tid & 3) == 0) {
    if (isq) { x2[row] = s; outp[row] = __uint_as_float(0x7f800000u); }
    else     { y2[row] = s; }
  }
}

__global__ __launch_bounds__(256, 4) void min_dist_kernel(
    const ushort* __restrict__ qbf, const ushort* __restrict__ tbf,
    const float* __restrict__ x2, const float* __restrict__ y2,
    float* __restrict__ outp)
{
  __shared__ __align__(16) float ldsY[TCHUNK];   // 4 KB, staged once

  const int tid  = threadIdx.x;
  const int w    = tid >> 6;
  const int lane = tid & 63;
  const int quad = lane >> 4;
  const int n    = lane & 15;
  const int tsplit = blockIdx.x & (TSPLIT - 1);   // -> XCD tsplit%8
  const int qblock = blockIdx.x / TSPLIT;
  const int qbase  = qblock * QB + w * 64;
  const int trow0  = tsplit * TCHUNK;

  // stage this chunk's y2 (1024 f32) into LDS
  *(float4*)&ldsY[tid * 4] = *(const float4*)(y2 + trow0 + tid * 4);

  // B-operand (query) fragments: 4 col-tiles x 3 k-blocks = 48 VGPRs.
  // volatile: forbid sinking these loads into the K-loop (R4/R5 pathology).
  bf16x8 bq[4][3];
  #pragma unroll
  for (int ct = 0; ct < 4; ++ct) {
    const ushort* qp = qbf + (size_t)(qbase + ct * 16 + n) * KD + quad * 8;
    #pragma unroll
    for (int kb = 0; kb < 3; ++kb)
      bq[ct][kb] = *(const volatile bf16x8*)(qp + kb * 32);
  }
  __syncthreads();   // ldsY ready

  const float INF = __uint_as_float(0x7f800000u);
  float m0 = INF, m1 = INF, m2 = INF, m3 = INF;

  // fragment-major train: one contiguous 1KB load per (group, kb)
  const ushort* tp = tbf + (size_t)(trow0 >> 4) * GRP_USH + lane * 8;

  bf16x8 a0 = *(const bf16x8*)(tp);
  bf16x8 a1 = *(const bf16x8*)(tp + 512);
  bf16x8 a2 = *(const bf16x8*)(tp + 1024);
  tp += GRP_USH;

  #pragma unroll 1
  for (int t = 0; t < NTT - 1; ++t) {
    bf16x8 na0 = *(const bf16x8*)(tp);
    bf16x8 na1 = *(const bf16x8*)(tp + 512);
    bf16x8 na2 = *(const bf16x8*)(tp + 1024);
    tp += GRP_USH;
    f32x4 y2v = *(const f32x4*)&ldsY[t * 16 + quad * 4];

    f32x4 acc;
    acc = __builtin_amdgcn_mfma_f32_16x16x32_bf16(a0, bq[0][0], y2v, 0, 0, 0);
    acc = __builtin_amdgcn_mfma_f32_16x16x32_bf16(a1, bq[0][1], acc, 0, 0, 0);
    acc = __builtin_amdgcn_mfma_f32_16x16x32_bf16(a2, bq[0][2], acc, 0, 0, 0);
    m0 = fminf(fminf(fminf(acc[0], acc[1]), acc[2]), fminf(acc[3], m0));

    acc = __builtin_amdgcn_mfma_f32_16x16x32_bf16(a0, bq[1][0], y2v, 0, 0, 0);
    acc = __builtin_amdgcn_mfma_f32_16x16x32_bf16(a1, bq[1][1], acc, 0, 0, 0);
    acc = __builtin_amdgcn_mfma_f32_16x16x32_bf16(a2, bq[1][2], acc, 0, 0, 0);
    m1 = fminf(fminf(fminf(acc[0], acc[1]), acc[2]), fminf(acc[3], m1));

    acc = __builtin_amdgcn_mfma_f32_16x16x32_bf16(a0, bq[2][0], y2v, 0, 0, 0);
    acc = __builtin_amdgcn_mfma_f32_16x16x32_bf16(a1, bq[2][1], acc, 0, 0, 0);
    acc = __builtin_amdgcn_mfma_f32_16x16x32_bf16(a2, bq[2][2], acc, 0, 0, 0);
    m2 = fminf(fminf(fminf(acc[0], acc[1]), acc[2]), fminf(acc[3], m2));

    acc = __builtin_amdgcn_mfma_f32_16x16x32_bf16(a0, bq[3][0], y2v, 0, 0, 0);
    acc = __builtin_amdgcn_mfma_f32_16x16x32_bf16(a1, bq[3][1], acc, 0, 0, 0);
    acc = __builtin_amdgcn_mfma_f32_16x16x32_bf16(a2, bq[3][2], acc, 0, 0, 0);
    m3 = fminf(fminf(fminf(acc[0], acc[1]), acc[2]), fminf(acc[3], m3));

    a0 = na0; a1 = na1; a2 = na2;
  }
  {  // final tile, no prefetch
    f32x4 y2v = *(const f32x4*)&ldsY[(NTT - 1) * 16 + quad * 4];
    f32x4 acc;
    acc = __builtin_amdgcn_mfma_f32_16x16x32_bf16(a0, bq[0][0], y2v, 0, 0, 0);
    acc = __builtin_amdgcn_mfma_f32_16x16x32_bf16(a1, bq[0][1], acc, 0, 0, 0);
    acc = __builtin_amdgcn_mfma_f32_16x16x32_bf16(a2, bq[0][2], acc, 0, 0, 0);
    m0 = fminf(fminf(fminf(acc[0], acc[1]), acc[2]), fminf(acc[3], m0));

    acc = __builtin_amdgcn_mfma_f32_16x16x32_bf16(a0, bq[1][0], y2v, 0, 0, 0);
    acc = __builtin_amdgcn_mfma_f32_16x16x32_bf16(a1, bq[1][1], acc, 0, 0, 0);
    acc = __builtin_amdgcn_mfma_f32_16x16x32_bf16(a2, bq[1][2], acc, 0, 0, 0);
    m1 = fminf(fminf(fminf(acc[0], acc[1]), acc[2]), fminf(acc[3], m1));

    acc = __builtin_amdgcn_mfma_f32_16x16x32_bf16(a0, bq[2][0], y2v, 0, 0, 0);
    acc = __builtin_amdgcn_mfma_f32_16x16x32_bf16(a1, bq[2][1], acc, 0, 0, 0);
    acc = __builtin_amdgcn_mfma_f32_16x16x32_bf16(a2, bq[2][2], acc, 0, 0, 0);
    m2 = fminf(fminf(fminf(acc[0], acc[1]), acc[2]), fminf(acc[3], m2));

    acc = __builtin_amdgcn_mfma_f32_16x16x32_bf16(a0, bq[3][0], y2v, 0, 0, 0);
    acc = __builtin_amdgcn_mfma_f32_16x16x32_bf16(a1, bq[3][1], acc, 0, 0, 0);
    acc = __builtin_amdgcn_mfma_f32_16x16x32_bf16(a2, bq[3][2], acc, 0, 0, 0);
    m3 = fminf(fminf(fminf(acc[0], acc[1]), acc[2]), fminf(acc[3], m3));
  }

  // fold across quads (lanes with equal n hold the same query columns)
  float m[4] = {m0, m1, m2, m3};
  #pragma unroll
  for (int ct = 0; ct < 4; ++ct) {
    m[ct] = fminf(m[ct], __shfl_xor(m[ct], 16, 64));
    m[ct] = fminf(m[ct], __shfl_xor(m[ct], 32, 64));
  }
  if (quad == 0) {
    #pragma unroll
    for (int ct = 0; ct < 4; ++ct) {
      int q = qbase + ct * 16 + n;
      float sq = fmaxf(x2[q] + m[ct], 0.0f);
      float val = sqrtf(sq) * 10.0f;
      atomicMin((unsigned int*)&outp[q], __float_as_uint(val));
    }
  }
}

extern "C" void kernel_launch(void* const* d_in, const int* in_sizes, int n_in,
                              void* d_out, int out_size, void* d_ws, size_t ws_size,
                              hipStream_t stream) {
  const float* qf = (const float*)d_in[0];   // mutation_dist 8192x96
  const float* tf = (const float*)d_in[1];   // train_data   65536x96
  float* outp = (float*)d_out;               // 8192 f32

  ushort* qbf = (ushort*)d_ws;                // 8192*96 bf16, row-major
  ushort* tbf = qbf + (size_t)NQ * KD;        // 65536*96 bf16, frag-major, -2x
  float* x2 = (float*)(tbf + (size_t)NT * KD);
  float* y2 = x2 + NQ;

  prep_kernel<<<(NQ + NT) / 64, 256, 0, stream>>>(qf, tf, qbf, tbf, x2, y2, outp);
  min_dist_kernel<<<(NQ / QB) * TSPLIT, 256, 0, stream>>>(qbf, tbf, x2, y2, outp);
}